// Round 16
// baseline (1120.327 us; speedup 1.0000x reference)
//
#include <hip/hip_runtime.h>

#define SEQ 2048
#define BATCH 512
#define HDIM 128

typedef __bf16 bf16x8 __attribute__((ext_vector_type(8)));
typedef float  f32x4  __attribute__((ext_vector_type(4)));
typedef unsigned int uint32;

// tanh with input pre-scaled by 2*log2(e): tanh(x) = 1 - 2/(2^(CS*x)+1).
__device__ __forceinline__ float tanh_e2(float y) {
    float e;
    asm("v_exp_f32 %0, %1" : "=v"(e) : "v"(y));
    return fmaf(-2.0f, __builtin_amdgcn_rcpf(e + 1.0f), 1.0f);
}

// x + dpp(x); bound_ctrl=true.
template<int CTRL>
__device__ __forceinline__ float dpp_add(float x) {
    return x + __int_as_float(__builtin_amdgcn_update_dpp(
        0, __float_as_int(x), CTRL, 0xf, 0xf, true));
}

__global__ __launch_bounds__(512, 2)
void odenet_scan_kernel(const float* __restrict__ x,
                        const float* __restrict__ W1,
                        const float* __restrict__ b1,
                        const float* __restrict__ W2,
                        const float* __restrict__ b2,
                        const float* __restrict__ W3,
                        const float* __restrict__ b3,
                        float* __restrict__ out)
{
    const int t  = threadIdx.x;
    const int l  = t & 63;           // lane
    const int wv = t >> 6;           // wave 0..7: owns output cols [16wv, 16wv+16)
    const int b0 = 2 * blockIdx.x;   // TWO chains per block (M-packed): b0, b0+1

    constexpr float CS = 2.8853900817779268f;   // 2*log2(e) tanh prefold

    __shared__ float2 xbuf[SEQ];                 // 16 KB: {xA, xB} per step
    // h staging, block-shared: rows 0..3 = chA-hi, chA-lo, chB-hi, chB-lo.
    // Row stride 144 ushorts = 288 B (proven conflict-free in R13/R14).
    __shared__ unsigned short hbuf[4 * 144];
    __shared__ __align__(16) float2 ybuf[8];     // per-wave {yA, yB} partials

    // ---- one-time: preload x for both chains (adjacent in memory).
    #pragma unroll
    for (int i = 0; i < 4; ++i)
        xbuf[i * 512 + t] = *reinterpret_cast<const float2*>(&x[(i * 512 + t) * BATCH + b0]);

    // ---- one-time: B fragments (CS*W2 hi/lo) for this wave's 16 cols.
    bf16x8 Bhi[4], Blo[4];
    const int bc = 16 * wv + (l & 15);           // this lane's B/C column
    #pragma unroll
    for (int kt = 0; kt < 4; ++kt) {
        union { unsigned short u[8]; bf16x8 v; } fh, fl;
        #pragma unroll
        for (int j = 0; j < 8; ++j) {
            const int k = 32 * kt + 8 * (l >> 4) + j;
            const float v = W2[k * HDIM + bc] * CS;
            const uint32 u = __float_as_uint(v);
            fh.u[j] = (unsigned short)(u >> 16);
            const float hif = __uint_as_float(u & 0xffff0000u);
            fl.u[j] = (unsigned short)(__float_as_uint(v - hif) >> 16);
        }
        Bhi[kt] = fh.v;
        Blo[kt] = fl.v;
    }

    // ---- layer-2/3 params.
    const float b2v = b2[bc] * CS;
    const float w3v = W3[2 * bc + 1];
    const float b31 = b3[1];

    // ---- layer-1 specialization: thread t<256 owns (chain = t>>7, col = t&127).
    const int hcol = t & 127;
    const int hch  = t >> 7;         // 0 = chain A, 1 = chain B (valid for t<256)
    float w1xv = 0.0f, w1sv = 0.0f, b1vv = 0.0f;
    if (t < 256) {
        w1xv = W1[hcol] * CS;
        w1sv = W1[HDIM + hcol] * CS;
        b1vv = b1[hcol] * CS;
    }
    unsigned short* pWhi = &hbuf[(2 * hch + 0) * 144 + hcol];
    unsigned short* pWlo = &hbuf[(2 * hch + 1) * 144 + hcol];

    // ---- A-frag read: lane (A-row l&15) loads h-row (l&3); rows 4-15 become
    //      harmless duplicates. Banks: 8*(l&3)+4*(l>>4), 2-addr/bank = free.
    const unsigned short* pA = &hbuf[(l & 3) * 144 + 8 * (l >> 4)];

    __syncthreads();   // x preload visible

    float s = 0.0f, s_hold = 0.0f;

    // ---- prologue: h(0) (s = 0).
    if (t < 256) {
        const float2 x0 = xbuf[0];
        const float h = tanh_e2(fmaf(w1xv, hch ? x0.y : x0.x, b1vv));
        const uint32 u = __float_as_uint(h);
        *pWhi = (unsigned short)(u >> 16);
        const float hf = __uint_as_float(u & 0xffff0000u);
        *pWlo = (unsigned short)(__float_as_uint(h - hf) >> 16);
    }
    __syncthreads();   // B1(0): h(0) visible

    for (int n = 0; n < SEQ; ++n) {
        // hoist next-x fold (off critical path)
        float pre1 = 0.0f;
        if (t < 256) {
            const float2 xn2 = xbuf[(n + 1) & (SEQ - 1)];
            pre1 = fmaf(w1xv, hch ? xn2.y : xn2.x, b1vv);
        }

        // ---- MFMA phase (all 8 waves): 8 MFMA serve BOTH chains.
        f32x4 Ch = {0.0f, 0.0f, 0.0f, 0.0f};
        f32x4 Cl = {0.0f, 0.0f, 0.0f, 0.0f};
        #pragma unroll
        for (int kt = 0; kt < 4; ++kt) {
            const bf16x8 a = __builtin_bit_cast(bf16x8,
                *reinterpret_cast<const uint4*>(pA + 32 * kt));
            Ch = __builtin_amdgcn_mfma_f32_16x16x32_bf16(a, Bhi[kt], Ch, 0, 0, 0);
            Cl = __builtin_amdgcn_mfma_f32_16x16x32_bf16(a, Blo[kt], Cl, 0, 0, 0);
        }
        // 3-term combine per chain (regs 0-3 = rows {Ahi,Alo,Bhi,Blo} pattern,
        // valid on every lane thanks to the row-dup trick) + tanh + w3.
        const float pAv = (Ch[0] + Ch[1]) + (Cl[0] + b2v);   // chain A
        const float pBv = (Ch[2] + Ch[3]) + (Cl[2] + b2v);   // chain B
        float zA = tanh_e2(pAv) * w3v;
        float zB = tanh_e2(pBv) * w3v;
        // reduce over this wave's 16 cols: xor1, xor2, xor4, xor8.
        zA = dpp_add<0xB1>(zA);   zB = dpp_add<0xB1>(zB);
        zA = dpp_add<0x4E>(zA);   zB = dpp_add<0x4E>(zB);
        zA = dpp_add<0x141>(zA);  zB = dpp_add<0x141>(zB);
        zA = dpp_add<0x140>(zA);  zB = dpp_add<0x140>(zB);
        if (l == 0) ybuf[wv] = make_float2(zA, zB);
        __syncthreads();   // B2(n): y visible; all h(n) LDS reads drained

        // ---- s + h phase (threads 0-255 only; waves 4-7 pass to B1).
        if (t < 256) {
            const float4* yq = reinterpret_cast<const float4*>(&ybuf[0]);
            const float4 q0 = yq[0], q1 = yq[1], q2 = yq[2], q3 = yq[3];
            const float dyA = ((q0.x + q0.z) + (q1.x + q1.z))
                            + ((q2.x + q2.z) + (q3.x + q3.z)) + b31;
            const float dyB = ((q0.y + q0.w) + (q1.y + q1.w))
                            + ((q2.y + q2.w) + (q3.y + q3.w)) + b31;
            s += hch ? dyB : dyA;

            // out batching: threads 0-63 hold chain A, 128-191 chain B.
            if ((t & 127) < 64) {
                if (l == (n & 63)) s_hold = s;
                if ((n & 63) == 63) out[(n - 63 + l) * BATCH + b0 + hch] = s_hold;
            }

            // h(n+1): one column per thread; hi/lo bf16 split -> LDS.
            const float h = tanh_e2(fmaf(w1sv, s, pre1));
            const uint32 u = __float_as_uint(h);
            *pWhi = (unsigned short)(u >> 16);
            const float hf = __uint_as_float(u & 0xffff0000u);
            *pWlo = (unsigned short)(__float_as_uint(h - hf) >> 16);
        }
        __syncthreads();   // B1(n+1): h(n+1) visible
    }
}

extern "C" void kernel_launch(void* const* d_in, const int* in_sizes, int n_in,
                              void* d_out, int out_size, void* d_ws, size_t ws_size,
                              hipStream_t stream) {
    const float* x  = (const float*)d_in[0];
    const float* W1 = (const float*)d_in[1];
    const float* b1 = (const float*)d_in[2];
    const float* W2 = (const float*)d_in[3];
    const float* b2 = (const float*)d_in[4];
    const float* W3 = (const float*)d_in[5];
    const float* b3 = (const float*)d_in[6];
    float* out = (float*)d_out;

    dim3 grid(BATCH / 2);   // 2 chains per block, M-packed
    dim3 block(512);        // 8 waves; layer-1 specialized to threads 0-255
    odenet_scan_kernel<<<grid, block, 0, stream>>>(x, W1, b1, W2, b2, W3, b3, out);
}

// Round 17
// 943.923 us; speedup vs baseline: 1.1869x; 1.1869x over previous
//
#include <hip/hip_runtime.h>

#define SEQ 2048
#define BATCH 512
#define HDIM 128

typedef __bf16 bf16x8 __attribute__((ext_vector_type(8)));
typedef float  f32x4  __attribute__((ext_vector_type(4)));
typedef unsigned int uint32;

// tanh with input pre-scaled by 2*log2(e): tanh(x) = 1 - 2/(2^(CS*x)+1).
__device__ __forceinline__ float tanh_e2(float y) {
    float e;
    asm("v_exp_f32 %0, %1" : "=v"(e) : "v"(y));
    return fmaf(-2.0f, __builtin_amdgcn_rcpf(e + 1.0f), 1.0f);
}

// x + dpp(x); bound_ctrl=true.
template<int CTRL>
__device__ __forceinline__ float dpp_add(float x) {
    return x + __int_as_float(__builtin_amdgcn_update_dpp(
        0, __float_as_int(x), CTRL, 0xf, 0xf, true));
}

__global__ __launch_bounds__(256, 2)
void odenet_scan_kernel(const float* __restrict__ x,
                        const float* __restrict__ W1,
                        const float* __restrict__ b1,
                        const float* __restrict__ W2,
                        const float* __restrict__ b2,
                        const float* __restrict__ W3,
                        const float* __restrict__ b3,
                        float* __restrict__ out)
{
    const int t  = threadIdx.x;
    const int l  = t & 63;           // lane
    const int wv = t >> 6;           // wave 0..3: owns output cols [32wv, 32wv+32)
    const int b  = blockIdx.x;       // ONE chain per block; grid=512 -> 2 blocks/CU

    constexpr float CS = 2.8853900817779268f;   // 2*log2(e) tanh prefold

    __shared__ float xbuf[SEQ];                        // 8 KB: all x for this chain
    // A-matrix staging: row0 = h_hi (bf16), row1 = h_lo. Row stride 144 ushorts
    // = 288 B = 72 banks === 8 (mod 32): row0/row1 readers hit disjoint banks.
    __shared__ unsigned short hbuf[4][2][144];         // [wave][row][k padded]
    __shared__ __align__(16) float ybuf[2][4];         // [parity][wave] y-partials

    // ---- one-time: preload x.
    #pragma unroll
    for (int i = 0; i < 8; ++i)
        xbuf[i * 256 + t] = x[(i * 256 + t) * BATCH + b];

    // ---- one-time: B fragments (CS*W2 split into bf16 hi/lo), pinned in regs.
    // 16x16x32 B-frag: lane holds col = l&15, k = 32*kt + 8*(l>>4) + j.
    bf16x8 Bhi[2][4], Blo[2][4];
    #pragma unroll
    for (int nt = 0; nt < 2; ++nt) {
        #pragma unroll
        for (int kt = 0; kt < 4; ++kt) {
            union { unsigned short u[8]; bf16x8 v; } fh, fl;
            #pragma unroll
            for (int j = 0; j < 8; ++j) {
                const int k = 32 * kt + 8 * (l >> 4) + j;
                const int c = 32 * wv + 16 * nt + (l & 15);
                const float v = W2[k * HDIM + c] * CS;
                const uint32 u = __float_as_uint(v);
                fh.u[j] = (unsigned short)(u >> 16);
                const float hif = __uint_as_float(u & 0xffff0000u);
                fl.u[j] = (unsigned short)(__float_as_uint(v - hif) >> 16);
            }
            Bhi[nt][kt] = fh.v;
            Blo[nt][kt] = fl.v;
        }
    }

    // ---- layer-1 params: this lane computes h cols 2l, 2l+1 (prescaled CS).
    const float2 w1x_ = *reinterpret_cast<const float2*>(&W1[2 * l]);
    const float2 w1s_ = *reinterpret_cast<const float2*>(&W1[HDIM + 2 * l]);
    const float2 b1v_ = *reinterpret_cast<const float2*>(&b1[2 * l]);
    const float2 w1x = make_float2(w1x_.x * CS, w1x_.y * CS);
    const float2 w1s = make_float2(w1s_.x * CS, w1s_.y * CS);
    const float2 b1v = make_float2(b1v_.x * CS, b1v_.y * CS);

    // ---- layer-2/3 params for this lane's two C-columns (cz, cz+16).
    const int cz = 32 * wv + (l & 15);
    const float b2a = b2[cz] * CS,  b2b = b2[cz + 16] * CS;
    const float w3a = W3[2 * cz + 1], w3b = W3[2 * (cz + 16) + 1];
    const float b31 = b3[1];

    // ---- LDS addresses.
    uint32* pWh = reinterpret_cast<uint32*>(&hbuf[wv][0][2 * l]);  // hi row
    uint32* pWl = reinterpret_cast<uint32*>(&hbuf[wv][1][2 * l]);  // lo row
    // A-frag read: lane supplies A[row=l&15]; row0=hi, row1=lo, rows 2-15 read
    // the lo row harmlessly (their C rows are never used).
    const int rowe = ((l & 15) == 0) ? 0 : 1;
    const unsigned short* pA = &hbuf[wv][rowe][8 * (l >> 4)];

    __syncthreads();

    float s = 0.0f, s_hold = 0.0f;
    float2 pre1 = make_float2(fmaf(w1x.x, xbuf[0], b1v.x),
                              fmaf(w1x.y, xbuf[0], b1v.y));

    for (int n = 0; n < SEQ; ++n) {
        const int par = n & 1;

        // ---- layer 1: 2 h cols; split to bf16 hi/lo; -> LDS rows 0/1.
        const float h0 = tanh_e2(fmaf(w1s.x, s, pre1.x));
        const float h1 = tanh_e2(fmaf(w1s.y, s, pre1.y));
        const uint32 u0 = __float_as_uint(h0), u1 = __float_as_uint(h1);
        const uint32 hi01 = __builtin_amdgcn_perm(u1, u0, 0x07060302u);
        const float r0 = h0 - __uint_as_float(u0 & 0xffff0000u);
        const float r1 = h1 - __uint_as_float(u1 & 0xffff0000u);
        const uint32 lo01 = __builtin_amdgcn_perm(
            __float_as_uint(r1), __float_as_uint(r0), 0x07060302u);
        *pWh = hi01;
        *pWl = lo01;
        __builtin_amdgcn_wave_barrier();   // in-wave LDS write -> read order

        // next pre1 (broadcast read, off critical path)
        const float xnext = xbuf[(n + 1) & (SEQ - 1)];
        pre1 = make_float2(fmaf(w1x.x, xnext, b1v.x), fmaf(w1x.y, xnext, b1v.y));

        // ---- matvec on matrix pipe: 4 independent accum chains, 16 MFMA.
        // T5: raise wave priority across the MFMA cluster — pays off because
        // the co-resident wave (other block) is at a different phase.
        f32x4 Ch0 = {b2a, b2a, b2a, b2a};
        f32x4 Ch1 = {b2b, b2b, b2b, b2b};
        f32x4 Cl0 = {0.0f, 0.0f, 0.0f, 0.0f};
        f32x4 Cl1 = {0.0f, 0.0f, 0.0f, 0.0f};
        __builtin_amdgcn_s_setprio(1);
        #pragma unroll
        for (int kt = 0; kt < 4; ++kt) {
            const bf16x8 a = __builtin_bit_cast(bf16x8,
                *reinterpret_cast<const uint4*>(pA + 32 * kt));
            Ch0 = __builtin_amdgcn_mfma_f32_16x16x32_bf16(a, Bhi[0][kt], Ch0, 0, 0, 0);
            Ch1 = __builtin_amdgcn_mfma_f32_16x16x32_bf16(a, Bhi[1][kt], Ch1, 0, 0, 0);
            Cl0 = __builtin_amdgcn_mfma_f32_16x16x32_bf16(a, Blo[0][kt], Cl0, 0, 0, 0);
            Cl1 = __builtin_amdgcn_mfma_f32_16x16x32_bf16(a, Blo[1][kt], Cl1, 0, 0, 0);
        }
        __builtin_amdgcn_s_setprio(0);
        __builtin_amdgcn_wave_barrier();   // reads precede next iter's writes

        // ---- combine 3 exact terms (valid on lanes 0-15: rows 0,1 live there).
        const float p0 = (Ch0[0] + Ch0[1]) + Cl0[0];
        const float p1 = (Ch1[0] + Ch1[1]) + Cl1[0];
        float z = fmaf(tanh_e2(p1), w3b, tanh_e2(p0) * w3a);

        // ---- reduce over 16 cols (lanes 0-15): xor1, xor2, xor4, xor8.
        z = dpp_add<0xB1>(z);    // quad_perm xor1
        z = dpp_add<0x4E>(z);    // quad_perm xor2
        z = dpp_add<0x141>(z);   // row_half_mirror == xor4 (quad-uniform)
        z = dpp_add<0x140>(z);   // row_mirror == xor8 (8-uniform)

        if (l == 0) ybuf[par][wv] = z;
        __syncthreads();   // the ONLY block barrier per step (vmcnt already 0)

        const float4 yv = *reinterpret_cast<const float4*>(&ybuf[par][0]);
        s += ((yv.x + yv.y) + (yv.z + yv.w)) + b31;

        // ---- out batching (wave 0): one scatter store per 64 steps.
        if (wv == 0) {
            if (l == (n & 63)) s_hold = s;
            if ((n & 63) == 63) out[(n - 63 + l) * BATCH + b] = s_hold;
        }
    }
}

extern "C" void kernel_launch(void* const* d_in, const int* in_sizes, int n_in,
                              void* d_out, int out_size, void* d_ws, size_t ws_size,
                              hipStream_t stream) {
    const float* x  = (const float*)d_in[0];
    const float* W1 = (const float*)d_in[1];
    const float* b1 = (const float*)d_in[2];
    const float* W2 = (const float*)d_in[3];
    const float* b2 = (const float*)d_in[4];
    const float* W3 = (const float*)d_in[5];
    const float* b3 = (const float*)d_in[6];
    float* out = (float*)d_out;

    dim3 grid(BATCH);    // one chain per block -> 2 independent blocks/CU
    dim3 block(256);     // 4 waves, 32 N-cols each
    odenet_scan_kernel<<<grid, block, 0, stream>>>(x, W1, b1, W2, b2, W3, b3, out);
}